// Round 5
// baseline (339.885 us; speedup 1.0000x reference)
//
#include <hip/hip_runtime.h>
#include <hip/hip_bf16.h>
#include <stdint.h>

typedef __attribute__((ext_vector_type(8))) __bf16 bf16x8;
typedef __attribute__((ext_vector_type(4))) float f32x4;

constexpr int K_DIM = 4096;
constexpr int N_DIM = 11008;
constexpr int M_DIM = 256;   // B*S
constexpr int TM = 256;      // full M per block
constexpr int TN = 64;       // N cols per block
constexpr int BK = 64;       // K per tile
constexpr int NT = 512;      // 8 waves: 4M x 2N, each wave 64M x 32N
constexpr int KT_ALL = K_DIM / BK;   // 64
constexpr int KSPLIT = 3;    // grid = 172*3 = 516 ~ 2.02 blocks/CU (balanced)

__device__ __forceinline__ void gload_lds16(const __bf16* gptr, __bf16* lptr) {
  __builtin_amdgcn_global_load_lds(
      (const __attribute__((address_space(1))) uint32_t*)gptr,
      (__attribute__((address_space(3))) uint32_t*)lptr, 16, 0, 0);
}

__device__ __forceinline__ bf16x8 cvt8f(const float4 u0, const float4 u1) {
  bf16x8 v;
  v[0] = (__bf16)u0.x; v[1] = (__bf16)u0.y; v[2] = (__bf16)u0.z; v[3] = (__bf16)u0.w;
  v[4] = (__bf16)u1.x; v[5] = (__bf16)u1.y; v[6] = (__bf16)u1.z; v[7] = (__bf16)u1.w;
  return v;
}
__device__ __forceinline__ bf16x8 cvt8i(const int4 a, const int4 b) {
  bf16x8 v;
  v[0] = (__bf16)(float)a.x; v[1] = (__bf16)(float)a.y;
  v[2] = (__bf16)(float)a.z; v[3] = (__bf16)(float)a.w;
  v[4] = (__bf16)(float)b.x; v[5] = (__bf16)(float)b.y;
  v[6] = (__bf16)(float)b.z; v[7] = (__bf16)(float)b.w;
  return v;
}

// x fp32 [256][4096] -> xws bf16 row-major (coalesced both sides)
__global__ void cvt_x_kernel(const float* __restrict__ x, __bf16* __restrict__ ws) {
  const int i = (blockIdx.x * 256 + threadIdx.x) * 8;
  const float4 u0 = ((const float4*)(x + i))[0];
  const float4 u1 = ((const float4*)(x + i))[1];
  *(bf16x8*)(ws + i) = cvt8f(u0, u1);
}

// w int32 [11008][4096] -> wbf bf16, pure stream, max MLP:
// one thread per 32B (2 independent dwordx4 loads, one 16B store), no loops,
// no barriers, 5.6M threads -> HBM request queue stays full (m13 regime).
__global__ void cvt_w_kernel(const int* __restrict__ w, __bf16* __restrict__ wbf) {
  const size_t i = ((size_t)blockIdx.x * 256 + threadIdx.x) * 8;
  const int4 a = ((const int4*)(w + i))[0];
  const int4 b = ((const int4*)(w + i))[1];
  *(bf16x8*)(wbf + i) = cvt8i(a, b);
}

template<bool A_WS, bool W_WS>
__global__ __launch_bounds__(NT, 4) void int8_linear_kernel(
    const float* __restrict__ x,     // [256,4096] fp32 (fallback)
    const __bf16* __restrict__ xws,  // [256,4096] bf16 (A_WS)
    const int*   __restrict__ w,     // [11008,4096] int32 (fallback)
    const __bf16* __restrict__ wbf,  // [11008,4096] bf16 (W_WS)
    const float* __restrict__ scale, // [11008]
    const float* __restrict__ bias,  // [11008]
    float*       __restrict__ out)   // [256,11008] fp32, pre-zeroed, atomics
{
  // Both operands bf16, both staged by fire-and-forget gload_lds (W_WS path),
  // double-buffered, one barrier per phase. W is L3-resident (cvt_w just wrote
  // it) and A is L2-resident (2 MB) -> load latency is L2/L3-class and covered
  // by the compute phase. XOR chunk swizzle applied on the SOURCE address
  // (linear LDS dest, rule #21); frag ds_read_b128 stays 2-way/free.
  __shared__ __bf16 As[2][TM * BK];    // 2 x 32 KB
  __shared__ __bf16 Wsh[2][TN * BK];   // 2 x 8 KB  -> 80 KB, 2 blocks/CU

  const int tid  = threadIdx.x;
  const int lane = tid & 63;
  const int wv   = tid >> 6;
  const int quad = lane >> 4;
  const int l16  = lane & 15;
  const int m_base = (wv >> 1) * 64;   // 4 M-groups
  const int wn     = wv & 1;           // 2 N-groups
  const int n_base = blockIdx.x * TN;
  const int kc     = blockIdx.y;

  // split-K tile range over 64 tiles: {21,21,22}
  const int t0 = (kc * KT_ALL) / KSPLIT;
  const int t1 = ((kc + 1) * KT_ALL) / KSPLIT;
  const int ntile = t1 - t0;

  f32x4 acc[4][2];
#pragma unroll
  for (int i = 0; i < 4; ++i)
#pragma unroll
    for (int j = 0; j < 2; ++j) acc[i][j] = (f32x4){0.f, 0.f, 0.f, 0.f};

  // stage tile kt -> buffer buf. A: 2048 16B-chunks / 512 thr = 4 each.
  // LDS chunk c=(row=c>>3, slot=c&7) holds global chunk k8 = slot^(row&7).
  auto stage = [&](int t, int buf) {
    const int kt = t0 + t;
    if (A_WS) {
#pragma unroll
      for (int j = 0; j < 4; ++j) {
        const int c = j * 512 + tid;
        const int row = c >> 3;
        const int k8 = (c & 7) ^ (row & 7);
        gload_lds16(xws + (int64_t)row * K_DIM + kt * BK + k8 * 8, As[buf] + c * 8);
      }
    } else {
#pragma unroll
      for (int j = 0; j < 4; ++j) {
        const int c = j * 512 + tid;
        const int row = c >> 3;
        const int k8 = c & 7;
        const float* s = x + (int64_t)row * K_DIM + kt * BK + k8 * 8;
        const bf16x8 v = cvt8f(((const float4*)s)[0], ((const float4*)s)[1]);
        *(bf16x8*)(As[buf] + row * BK + (k8 ^ (row & 7)) * 8) = v;
      }
    }
    // W: 512 16B-chunks / 512 thr = 1 each (row = tid>>3, 8 slots/row)
    const int row = tid >> 3;
    const int k8l = tid & 7;
    if (W_WS) {
      const int k8 = k8l ^ (row & 7);
      gload_lds16(wbf + (int64_t)(n_base + row) * K_DIM + kt * BK + k8 * 8,
                  Wsh[buf] + tid * 8);
    } else {
      const int4* p = (const int4*)(w + (int64_t)(n_base + row) * K_DIM + kt * BK + k8l * 8);
      const bf16x8 v = cvt8i(p[0], p[1]);
      *(bf16x8*)(Wsh[buf] + row * BK + (k8l ^ (row & 7)) * 8) = v;
    }
  };
  auto compute = [&](const __bf16* abuf, const __bf16* wbuf) {
#pragma unroll
    for (int ks = 0; ks < 2; ++ks) {
      bf16x8 a[4], b[2];
#pragma unroll
      for (int mi = 0; mi < 4; ++mi) {
        const int m = m_base + mi * 16 + l16;
        const int slot = (ks * 4 + quad) ^ (m & 7);
        a[mi] = *(const bf16x8*)(abuf + m * BK + slot * 8);
      }
#pragma unroll
      for (int ni = 0; ni < 2; ++ni) {
        const int n = wn * 32 + ni * 16 + l16;
        const int slot = (ks * 4 + quad) ^ (n & 7);
        b[ni] = *(const bf16x8*)(wbuf + n * BK + slot * 8);
      }
#pragma unroll
      for (int mi = 0; mi < 4; ++mi)
#pragma unroll
        for (int ni = 0; ni < 2; ++ni)
          acc[mi][ni] = __builtin_amdgcn_mfma_f32_16x16x32_bf16(
              a[mi], b[ni], acc[mi][ni], 0, 0, 0);
    }
  };

  // m97 2-barrier loop: stage(t+1) issues BEFORE compute(t); the barrier's
  // vmcnt(0) drain lands after a full compute phase of latency cover.
  stage(0, 0);
  __syncthreads();
  for (int t = 0; t < ntile; ++t) {
    if (t + 1 < ntile) stage(t + 1, (t + 1) & 1);
    compute(As[t & 1], Wsh[t & 1]);
    __syncthreads();
  }

  // Epilogue: C/D layout col=lane&15, row=quad*4+reg (m89-verified).
  // Scale per-partial (linear); bias added exactly once by the kc==0 block.
#pragma unroll
  for (int ni = 0; ni < 2; ++ni) {
    const int col = n_base + wn * 32 + ni * 16 + l16;
    const float sc = scale[col];
    const float bi = (kc == 0) ? bias[col] : 0.0f;
#pragma unroll
    for (int mi = 0; mi < 4; ++mi) {
      const int row0 = m_base + mi * 16 + quad * 4;
#pragma unroll
      for (int r = 0; r < 4; ++r)
        unsafeAtomicAdd(out + (int64_t)(row0 + r) * N_DIM + col,
                        acc[mi][ni][r] * sc + bi);
    }
  }
}

extern "C" void kernel_launch(void* const* d_in, const int* in_sizes, int n_in,
                              void* d_out, int out_size, void* d_ws, size_t ws_size,
                              hipStream_t stream) {
  const float* x     = (const float*)d_in[0];
  const int*   w     = (const int*)d_in[1];
  const float* scale = (const float*)d_in[2];
  const float* bias  = (const float*)d_in[3];
  float* out = (float*)d_out;

  const size_t xws_bytes = (size_t)M_DIM * K_DIM * sizeof(__bf16);   // 2 MB
  const size_t wbf_bytes = (size_t)N_DIM * K_DIM * sizeof(__bf16);   // 90.2 MB
  __bf16* xws = (__bf16*)d_ws;
  __bf16* wbf = (__bf16*)((char*)d_ws + xws_bytes);

  // split-K partials accumulate via atomics -> zero the output first
  hipMemsetAsync(out, 0, (size_t)M_DIM * N_DIM * sizeof(float), stream);

  dim3 grid(N_DIM / TN, KSPLIT), block(NT);
  if (ws_size >= xws_bytes + wbf_bytes) {
    cvt_x_kernel<<<M_DIM * K_DIM / 2048, 256, 0, stream>>>(x, xws);
    cvt_w_kernel<<<(int)(((size_t)N_DIM * K_DIM) / 2048), 256, 0, stream>>>(w, wbf);
    int8_linear_kernel<true, true><<<grid, block, 0, stream>>>(
        x, xws, w, wbf, scale, bias, out);
  } else if (ws_size >= xws_bytes) {
    cvt_x_kernel<<<M_DIM * K_DIM / 2048, 256, 0, stream>>>(x, xws);
    int8_linear_kernel<true, false><<<grid, block, 0, stream>>>(
        x, xws, w, wbf, scale, bias, out);
  } else {
    int8_linear_kernel<false, false><<<grid, block, 0, stream>>>(
        x, xws, w, wbf, scale, bias, out);
  }
}